// Round 4
// baseline (324.581 us; speedup 1.0000x reference)
//
#include <hip/hip_runtime.h>
#include <math.h>

#define NN 1024
#define BATCH 32
#define P 8               // blocks (stages) per batch
#define NW 8              // waves per block (R4: 2 waves/SIMD for latency hiding)
#define THREADS 512       // NW * 64
#define DD 16             // diagonals per interval (needs SW >= DD-1)
#define SW 16             // row stride between waves
#define SPAN 176          // (NW-1)*SW + 64
#define NT 128            // 2048/DD (covers k=0..2047)
#define RB 2              // ring slots per interface (power of 2)
#define WLN 2400          // per-block unified weight LUT length (idx = t*DD+d+wq, wq in [0,350])
#define GW 0.05f
#define K2 144.2695040888963f            // (1/gamma)*log2(e): scaled domain
#define INV_K2 0.0069314718055994531f    // gamma*ln2
#define BIGS 1.4426950408889634e11f      // 1e9 * K2

#define EXP2F(x) __builtin_amdgcn_exp2f(x)
#define LOG2F(x) __builtin_amdgcn_logf(x)   // v_log_f32 = log2

typedef unsigned long long u64;

// lanes 1..63 <- src[lane-1]; lane 0 <- oldv[0] (DPP wave_shr:1, bound_ctrl=false)
__device__ __forceinline__ float dppshr(float oldv, float src) {
    return __int_as_float(__builtin_amdgcn_update_dpp(
        __float_as_int(oldv), __float_as_int(src), 0x138, 0xF, 0xF, false));
}

// self-validating packet: {f32 value | u32 tag} in one atomic u64
__device__ __forceinline__ u64 pk(float v, unsigned tag) {
    return ((u64)tag << 32) | (u64)__float_as_uint(v);
}

// zero acks[256] + all packet words (tags must not alias across runs)
// gx = 256 interfaces * RB * DD * 2 = 16384 u64 -> 64 blocks of 256
__global__ __launch_bounds__(256) void ws_init(int* __restrict__ acks,
                                               u64* __restrict__ gx) {
    if (blockIdx.x == 64) acks[threadIdx.x] = 0;
    else gx[(size_t)blockIdx.x * 256 + threadIdx.x] = 0;
}

// One DP step. DOMASK is compile-time 0/1; entry mask doubles as the i<0
// boundary (R(-1,j)=inf), so the wave containing rows i<0 keeps it forever.
#define STEPBODY(d, DOMASK) do {                                              \
        xv = dppshr(((d) == 0) ? xf0 : xv, xv);     /* x[k-i] flows diag */   \
        const float up = dppshr(((d) == 0) ? bndUp : r1, r1); /* R(i-1,k-1)*/ \
        const float dg = dgp;                                                 \
        const float left = r1;                                                \
        const float diff = ti - xv;                                           \
        const float dk = diff * diff * wreg[(d)];   /* K2-scaled cost */      \
        const float mn = fminf(fminf(dg, up), left);                          \
        const float md = __builtin_amdgcn_fmed3f(dg, up, left);               \
        const float mx = fmaxf(fmaxf(dg, up), left);                          \
        const float ss = 1.0f + EXP2F(mn - md) + EXP2F(mn - mx);              \
        float r = dk + mn - LOG2F(ss);                                        \
        if (DOMASK) r = (jj0 >= -(d)) ? r : BIGS;   /* entry-side mask */     \
        r2 = r1; r1 = r; dgp = up;                                            \
    } while (0)

// Overlapped-band wavefront soft-DTW, 8 CUs per batch.
// Round-8: TLP restructure. R3 counters: Occupancy 10% (1 wave/SIMD),
// VALUBusy 46% ~= inner-loop issue alone -> ~3000cy/interval of exposed
// latency with nothing to fill it. R2 proved 2 waves/SIMD gives 1.55x per-CU
// throughput but halved active CUs. Now: NW=8 waves x SW=16, DD=16, NT=128,
// 512-thread blocks -> 256 blocks on 256 CUs AND 2 waves/SIMD. Each SIMD
// hosts 2 waves of the same stage; one wave's chain/LDS stalls are filled by
// the other's issue. Handshake protocol (tagged packets, fire-and-forget,
// LDS-only barrier) unchanged.
__global__ __launch_bounds__(THREADS) void sdtw_pipe8(
        const float* __restrict__ inp, const float* __restrict__ tgt,
        float* __restrict__ partial, int* __restrict__ acks,
        u64* __restrict__ gx)
{
    __shared__ __align__(16) float xs[NN];
    __shared__ __align__(16) float wlu[WLN];
    __shared__ float2 exch[2][SPAN];

    const int bid = blockIdx.x;
    const int b = bid & 31;          // same-batch stages share an XCD (bid%8 = b%8)
    const int p = bid >> 5;
    const int tid = threadIdx.x;
    const int w = tid >> 6;
    const int lane = tid & 63;

    // unified LUT: wlu[idx] = K2*sigma(G*(|m-1023|-512)), m = idx + mlo.
    // m = k - 2i + 1023; i in [128p-15, 128p+160] -> idx = t*DD+d+wq with
    // wq = 320 + 256p - 2i in [0, 350]; mlo = 703 - 256p. Out-of-range m
    // only feeds masked/unread cells (finite benign value K2).
    const int mlo = 703 - 256 * p;
    for (int tdx = tid; tdx < NN; tdx += THREADS)
        xs[tdx] = inp[b * NN + tdx];
    for (int tdx = tid; tdx < WLN; tdx += THREADS) {
        int m = tdx + mlo;
        float val = K2;
        if ((unsigned)m <= 2046u)
            val = K2 / (1.0f + __expf(-GW * (fabsf((float)m - 1023.0f) - 512.0f)));
        wlu[tdx] = val;
    }

    const int i = 128 * p - (DD - 1) + SW * w + lane;   // owned row (may be OOB)
    const int i0 = i - lane;                            // wave's base row
    const bool rowValid = (unsigned)i < (unsigned)NN;
    int ic = min(max(i, 0), NN - 1);
    const float ti = tgt[b * NN + ic];
    const int imask = rowValid ? i : 0x3FFFFFFF;        // forces jj0 very negative
    // weight index at step d: t*DD + d + wq (wq even -> b64-aligned pairs)
    const int wq = 320 + 256 * p - 2 * i;
    const float* wpBase = &wlu[wq];

    float r1 = BIGS, r2 = BIGS;             // R(i,k-1), R(i,k-2), scaled by K2
    float dgp = (i == 0) ? 0.0f : BIGS;     // R(i-1,k-2) carry; R(-1,-1)=0
    float bndUp = BIGS;                     // lane-0 'up' feed at interval start
    float xv = 0.0f;                        // x[k - i] rotation register
    int ackC = 0;

    __syncthreads();                        // full sync once: LDS init done

    const int fin = b * P + p;              // inbound interface (p>0)
    const int fout = fin + 1;               // outbound interface (p<P-1)
    u64* gout = gx + (size_t)fout * (RB * DD * 2);
    u64* ginb = gx + (size_t)fin * (RB * DD * 2);

    const bool isProd = (w == NW - 1) && (p < P - 1);
    const bool isCons = (w == 0) && (p > 0);

    u64 pfA = 0, pfB = 0, pfC0 = 0, pfC1 = 0;   // consumer prefetch regs

    // ping-pong prefetch of the x rotation seeds for interval t=0
    int cP  = min(max(-1 - i, 0), NN - 1);
    int c0P = min(max(-i0, 0), NN - 1);
    float xpreA = xs[cP];       // -> xv init: x[kbase-1-i]
    float xpreB = xs[c0P];      // -> xf0:     x[kbase-i0]

    for (int t = 0; t < NT; ++t) {
        if (t > 0) {
            // ---- deferred cross-block publish of interval t-1 (tag = t) ----
            // r1/r2 of lanes DD-1..2DD-2 still hold interval t-1 finals here.
            if (isProd) {
                if (t > RB) {                       // slot (t-1)&1 free? need ack >= t-RB
                    while (ackC < t - RB) {
                        __builtin_amdgcn_s_sleep(1);
                        ackC = __hip_atomic_load(&acks[fout], __ATOMIC_RELAXED,
                                                 __HIP_MEMORY_SCOPE_AGENT);
                    }
                }
                if (lane >= DD - 1 && lane <= 2 * DD - 2) {
                    u64* gq = gout + (size_t)((t - 1) & (RB - 1)) * (DD * 2)
                                   + (size_t)(lane - (DD - 1)) * 2;
                    __hip_atomic_store(&gq[0], pk(r1, (unsigned)t),
                                       __ATOMIC_RELAXED, __HIP_MEMORY_SCOPE_AGENT);
                    __hip_atomic_store(&gq[1], pk(r2, (unsigned)t),
                                       __ATOMIC_RELAXED, __HIP_MEMORY_SCOPE_AGENT);
                }
                // ack prefetch for next gate; latency hides under inner loop
                ackC = __hip_atomic_load(&acks[fout], __ATOMIC_RELAXED,
                                         __HIP_MEMORY_SCOPE_AGENT);
            }
            // ---- refresh stale lanes (0..DD-2) + boundary feed ----
            if (w > 0) {
                const int buf = (t - 1) & 1;
                if (lane < DD - 1) { float2 vv = exch[buf][SW * w + lane]; r1 = vv.x; r2 = vv.y; }
                float2 bv = exch[buf][SW * w - 1];
                float nd = dppshr(0.0f, r2);
                if (lane == 0)           { bndUp = bv.x; dgp = bv.y; }
                else if (lane <= DD - 2) dgp = nd;
            } else if (p > 0) {
                // consumer: validate prefetched packets; fallback re-poll
                const unsigned expect = (unsigned)t;
                const u64* gslot = ginb + (size_t)((t - 1) & (RB - 1)) * (DD * 2);
                for (;;) {
                    int ok = 1;
                    if (lane < DD - 1)
                        ok = ((unsigned)(pfA >> 32) == expect) &
                             ((unsigned)(pfB >> 32) == expect);
                    if (lane == 0)
                        ok &= ((unsigned)(pfC0 >> 32) == expect) &
                              ((unsigned)(pfC1 >> 32) == expect);
                    if (__all(ok)) break;
                    if (lane < DD - 1) {
                        pfA = __hip_atomic_load((u64*)&gslot[(size_t)(lane + 1) * 2],
                                                __ATOMIC_RELAXED, __HIP_MEMORY_SCOPE_AGENT);
                        pfB = __hip_atomic_load((u64*)&gslot[(size_t)(lane + 1) * 2 + 1],
                                                __ATOMIC_RELAXED, __HIP_MEMORY_SCOPE_AGENT);
                    }
                    if (lane == 0) {
                        pfC0 = __hip_atomic_load((u64*)&gslot[0],
                                                 __ATOMIC_RELAXED, __HIP_MEMORY_SCOPE_AGENT);
                        pfC1 = __hip_atomic_load((u64*)&gslot[1],
                                                 __ATOMIC_RELAXED, __HIP_MEMORY_SCOPE_AGENT);
                    }
                }
                if (lane < DD - 1) { r1 = __uint_as_float((unsigned)pfA);
                                     r2 = __uint_as_float((unsigned)pfB); }
                float nd = dppshr(0.0f, r2);
                if (lane == 0) { bndUp = __uint_as_float((unsigned)pfC0);
                                 dgp   = __uint_as_float((unsigned)pfC1); }
                else if (lane <= DD - 2) dgp = nd;
                // ack value data-depends on loaded tag: cannot precede the loads
                if (lane == 0)
                    __hip_atomic_store(&acks[fin], (int)(pfC0 >> 32),
                                       __ATOMIC_RELAXED, __HIP_MEMORY_SCOPE_AGENT);
            } else {
                bndUp = BIGS;   // p==0, w==0: true boundary
            }
        }

        // ---- interval t compute ----
        const int kbase = t << 4;
        const int jj0 = kbase - imask;                  // j at d=0 (or very negative)

        // preload this interval's DD consecutive weights into registers
        // (DD/2 x ds_read_b64; removes per-step LDS latency from the chain)
        const float* wp = wpBase + kbase;
        float wreg[DD];
        #pragma unroll
        for (int h = 0; h < DD / 2; ++h) {
            float2 w2 = *reinterpret_cast<const float2*>(&wp[2 * h]);
            wreg[2 * h] = w2.x; wreg[2 * h + 1] = w2.y;
        }

        const float xf0 = xpreB;
        xv = xpreA;
        // issue next interval's x seeds now; full interval to complete
        { int cN  = min(max(kbase + DD - 1 - i, 0), NN - 1);
          int c0N = min(max(kbase + DD - i0, 0), NN - 1);
          xpreA = xs[cN]; xpreB = xs[c0N]; }

        if (i0 >= 0 && kbase >= i0 + 63) {
            // steady: every lane has j>=0 for all d; rows >1023 compute
            // garbage that is provably never consumed (dpp feeds upward only,
            // exch/cross-block publishes cover valid rows only)
            #pragma unroll
            for (int d = 0; d < DD; ++d) STEPBODY(d, 0);
        } else {
            #pragma unroll
            for (int d = 0; d < DD; ++d) STEPBODY(d, 1);
        }
        if (t == NT - 1) break;

        // intra-block publish: fresh lanes only (wave NW-1's slots are unread)
        if (w < NW - 1 && lane >= DD - 1)
            exch[t & 1][SW * w + lane] = make_float2(r1, r2);

        // consumer prefetch for next boundary (tag t+1, slot t&1): issued
        // pre-barrier so fabric latency overlaps barrier-wait + next refresh
        if (isCons) {
            const u64* gslot = ginb + (size_t)(t & (RB - 1)) * (DD * 2);
            if (lane < DD - 1) {
                pfA = __hip_atomic_load((u64*)&gslot[(size_t)(lane + 1) * 2],
                                        __ATOMIC_RELAXED, __HIP_MEMORY_SCOPE_AGENT);
                pfB = __hip_atomic_load((u64*)&gslot[(size_t)(lane + 1) * 2 + 1],
                                        __ATOMIC_RELAXED, __HIP_MEMORY_SCOPE_AGENT);
            }
            if (lane == 0) {
                pfC0 = __hip_atomic_load((u64*)&gslot[0],
                                         __ATOMIC_RELAXED, __HIP_MEMORY_SCOPE_AGENT);
                pfC1 = __hip_atomic_load((u64*)&gslot[1],
                                         __ATOMIC_RELAXED, __HIP_MEMORY_SCOPE_AGENT);
            }
        }

        // LDS-only barrier: drain ds_writes, leave global ops in flight.
        asm volatile("s_waitcnt lgkmcnt(0)" ::: "memory");
        __builtin_amdgcn_s_barrier();
        asm volatile("" ::: "memory");
        __builtin_amdgcn_sched_barrier(0);
    }

    // after t=NT-1: r2 = R(i, 2046); row 1023 appears in w=6 (lane 46) and
    // w=7 (lane 30) at p=7 -> both write the identical value (benign)
    if (i == NN - 1) partial[b] = r2 * INV_K2;
}

__global__ __launch_bounds__(64) void reduce_mean32(const float* __restrict__ partial,
                                                    float* __restrict__ out) {
    float v = (threadIdx.x < BATCH) ? partial[threadIdx.x] : 0.0f;
    #pragma unroll
    for (int off = 32; off > 0; off >>= 1) v += __shfl_down(v, off);
    if (threadIdx.x == 0) out[0] = v * (1.0f / (float)BATCH);
}

extern "C" void kernel_launch(void* const* d_in, const int* in_sizes, int n_in,
                              void* d_out, int out_size, void* d_ws, size_t ws_size,
                              hipStream_t stream) {
    const float* inp = (const float*)d_in[0];  // [B, N, 1]
    const float* tgt = (const float*)d_in[1];  // [B, N, 1]
    float* out = (float*)d_out;                // [1]

    float* partial = (float*)d_ws;                        // 32 floats
    int* acks  = (int*)((char*)d_ws + 128);               // 256 ints
    u64* gx    = (u64*)((char*)d_ws + 2048);              // 256*RB*DD*2 u64 = 128KB

    ws_init<<<65, 256, 0, stream>>>(acks, gx);
    sdtw_pipe8<<<BATCH * P, THREADS, 0, stream>>>(inp, tgt, partial, acks, gx);
    reduce_mean32<<<1, 64, 0, stream>>>(partial, out);
}

// Round 5
// 218.087 us; speedup vs baseline: 1.4883x; 1.4883x over previous
//
#include <hip/hip_runtime.h>
#include <math.h>

#define NN 1024
#define BATCH 32
#define P 8               // blocks per batch
#define NW 4              // waves per block
#define THREADS 256
#define DD 32             // diagonals per interval (needs SW >= DD-1, SW+DD <= 65)
#define SW 32             // row stride between waves
#define SPAN 160          // (NW-1)*SW + 64
#define NT 64             // ceil(2047/DD)
#define RB 2              // fabric ring slots per interface (power of 2)
#define EXB 4             // LDS exchange ring slots (power of 2)
#define WLN 2368          // per-block unified weight LUT length (covers m-range + guards)
#define GW 0.05f
#define K2 144.2695040888963f            // (1/gamma)*log2(e): scaled domain
#define INV_K2 0.0069314718055994531f    // gamma*ln2
#define BIGS 1.4426950408889634e11f      // 1e9 * K2

#define EXP2F(x) __builtin_amdgcn_exp2f(x)
#define LOG2F(x) __builtin_amdgcn_logf(x)   // v_log_f32 = log2

typedef unsigned long long u64;

// lanes 1..63 <- src[lane-1]; lane 0 <- oldv[0] (DPP wave_shr:1, bound_ctrl=false)
__device__ __forceinline__ float dppshr(float oldv, float src) {
    return __int_as_float(__builtin_amdgcn_update_dpp(
        __float_as_int(oldv), __float_as_int(src), 0x138, 0xF, 0xF, false));
}

// self-validating packet: {f32 value | u32 tag} in one atomic u64
__device__ __forceinline__ u64 pk(float v, unsigned tag) {
    return ((u64)tag << 32) | (u64)__float_as_uint(v);
}

// acquire-poll an LDS progress counter until >= want
__device__ __forceinline__ void waitProg(int* fp, int want) {
    while (__hip_atomic_load(fp, __ATOMIC_ACQUIRE, __HIP_MEMORY_SCOPE_WORKGROUP) < want)
        __builtin_amdgcn_s_sleep(1);
}

// zero acks[256] + all packet words (tags must not alias across runs)
__global__ __launch_bounds__(256) void ws_init(int* __restrict__ acks,
                                               u64* __restrict__ gx) {
    if (blockIdx.x == 128) acks[threadIdx.x] = 0;
    else gx[(size_t)blockIdx.x * 256 + threadIdx.x] = 0;  // 128*256 = 256*RB*DD*2
}

// One DP step. DOMASK is compile-time 0/1; entry mask doubles as the i<0
// boundary (R(-1,j)=inf), so the wave containing rows i<0 keeps it forever.
#define STEPBODY(d, DOMASK) do {                                              \
        xv = dppshr(((d) == 0) ? xf0 : xv, xv);     /* x[k-i] flows diag */   \
        const float up = dppshr(((d) == 0) ? bndUp : r1, r1); /* R(i-1,k-1)*/ \
        const float dg = dgp;                                                 \
        const float left = r1;                                                \
        const float diff = ti - xv;                                           \
        const float dk = diff * diff * wreg[(d)];   /* K2-scaled cost */      \
        const float mn = fminf(fminf(dg, up), left);                          \
        const float md = __builtin_amdgcn_fmed3f(dg, up, left);               \
        const float mx = fmaxf(fmaxf(dg, up), left);                          \
        const float ss = 1.0f + EXP2F(mn - md) + EXP2F(mn - mx);              \
        float r = dk + mn - LOG2F(ss);                                        \
        if (DOMASK) r = (jj0 >= -(d)) ? r : BIGS;   /* entry-side mask */     \
        r2 = r1; r1 = r; dgp = up;                                            \
    } while (0)

// Overlapped-band wavefront soft-DTW, 8 CUs per batch.
// Round-9: barrier removal. R4's controlled experiment isolated per-interval
// fixed overhead = 4,350 cy (70% of runtime) vs 48 cy/step chain. The
// s_barrier makes every wave absorb the slowest wave's boundary path (fabric
// validate/publish, exchange RT) each interval, and propagates jitter. The
// overlapped band already gives each wave one interval of data slack over its
// neighbor -- so replace the barrier with a per-wave LDS flag protocol:
// quad-buffered exch ring; wave w release-stores prog[w]=t after publishing;
// wave w+1 acquire-polls prog[w] >= t-1 before refresh; writers poll
// prog[w+1] >= t-3 for overwrite safety. Waves free-run; consumer stalls no
// longer block sibling waves. Everything else identical to R3.
__global__ __launch_bounds__(THREADS) void sdtw_pipe8(
        const float* __restrict__ inp, const float* __restrict__ tgt,
        float* __restrict__ partial, int* __restrict__ acks,
        u64* __restrict__ gx)
{
    __shared__ __align__(16) float xs[NN];
    __shared__ __align__(16) float wlu[WLN];
    __shared__ float2 exch[EXB][SPAN];
    __shared__ int prog[NW];

    const int bid = blockIdx.x;
    const int b = bid & 31;          // same-batch stages share an XCD (bid%8 = b%8)
    const int p = bid >> 5;
    const int tid = threadIdx.x;
    const int w = tid >> 6;
    const int lane = tid & 63;

    // unified LUT: wlu[idx] = K2*sigma(G*(|m-1023|-512)), m = idx + mlo.
    // Per-block m range: m = k - 2i + 1023, k in [0,2047], i in [128p-31,128p+128]
    // -> [767-256p, 3132-256p]; out-of-range m only feeds masked/unread cells
    // (finite benign value K2). mlo odd + m0 odd -> idx even -> 8B aligned.
    const int mlo = 767 - 256 * p;
    for (int tdx = tid; tdx < NN; tdx += THREADS)
        xs[tdx] = inp[b * NN + tdx];
    for (int tdx = tid; tdx < WLN; tdx += THREADS) {
        int m = tdx + mlo;
        float val = K2;
        if ((unsigned)m <= 2046u)
            val = K2 / (1.0f + __expf(-GW * (fabsf((float)m - 1023.0f) - 512.0f)));
        wlu[tdx] = val;
    }
    if (tid < NW) prog[tid] = -1;

    const int i = 128 * p - (DD - 1) + SW * w + lane;   // owned row (may be OOB)
    const int i0 = i - lane;                            // wave's base row
    const bool rowValid = (unsigned)i < (unsigned)NN;
    int ic = min(max(i, 0), NN - 1);
    const float ti = tgt[b * NN + ic];
    const int imask = rowValid ? i : 0x3FFFFFFF;        // forces jj0 very negative
    // weight index at step d: (t<<5) + wq + d, wq = 256 + 256p - 2i (even, in [0,318])
    const int wq = 256 + 256 * p - 2 * i;

    float r1 = BIGS, r2 = BIGS;             // R(i,k-1), R(i,k-2), scaled by K2
    float dgp = (i == 0) ? 0.0f : BIGS;     // R(i-1,k-2) carry; R(-1,-1)=0
    float bndUp = BIGS;                     // lane-0 'up' feed at interval start
    float xv = 0.0f;                        // x[k - i] rotation register
    int ackC = 0;

    __syncthreads();                        // full sync once: LDS init done

    const int fin = b * P + p;              // inbound interface (p>0)
    const int fout = fin + 1;               // outbound interface (p<P-1)
    u64* gout = gx + (size_t)fout * (RB * DD * 2);
    u64* ginb = gx + (size_t)fin * (RB * DD * 2);

    const bool isProd = (w == NW - 1) && (p < P - 1);
    const bool isCons = (w == 0) && (p > 0);

    u64 pfA = 0, pfB = 0, pfC0 = 0, pfC1 = 0;   // consumer prefetch regs

    // ping-pong prefetch of the x rotation seeds for interval t=0
    int cP  = min(max(-1 - i, 0), NN - 1);
    int c0P = min(max(-i0, 0), NN - 1);
    float xpreA = xs[cP];       // -> xv init: x[kbase-1-i]
    float xpreB = xs[c0P];      // -> xf0:     x[kbase-i0]

    for (int t = 0; t < NT; ++t) {
        if (t > 0) {
            // ---- deferred cross-block publish of interval t-1 (tag = t) ----
            // r1/r2 of lanes 31..62 still hold interval t-1 finals here
            // (refresh below only touches lanes 0..30).
            if (isProd) {
                if (t > RB) {                       // slot (t-1)&1 free? need ack >= t-RB
                    while (ackC < t - RB) {
                        __builtin_amdgcn_s_sleep(1);
                        ackC = __hip_atomic_load(&acks[fout], __ATOMIC_RELAXED,
                                                 __HIP_MEMORY_SCOPE_AGENT);
                    }
                }
                if (lane >= DD - 1 && lane < 63) {
                    u64* gq = gout + (size_t)((t - 1) & (RB - 1)) * (DD * 2)
                                   + (size_t)(lane - (DD - 1)) * 2;
                    __hip_atomic_store(&gq[0], pk(r1, (unsigned)t),
                                       __ATOMIC_RELAXED, __HIP_MEMORY_SCOPE_AGENT);
                    __hip_atomic_store(&gq[1], pk(r2, (unsigned)t),
                                       __ATOMIC_RELAXED, __HIP_MEMORY_SCOPE_AGENT);
                }
                // ack prefetch for next gate; latency hides under inner loop
                ackC = __hip_atomic_load(&acks[fout], __ATOMIC_RELAXED,
                                         __HIP_MEMORY_SCOPE_AGENT);
            }
            // ---- refresh stale lanes (0..30) + boundary feed ----
            if (w > 0) {
                waitProg(&prog[w - 1], t - 1);      // neighbor published t-1
                const int buf = (t - 1) & (EXB - 1);
                if (lane < DD - 1) { float2 vv = exch[buf][SW * w + lane]; r1 = vv.x; r2 = vv.y; }
                float2 bv = exch[buf][SW * w - 1];
                float nd = dppshr(0.0f, r2);
                if (lane == 0)           { bndUp = bv.x; dgp = bv.y; }
                else if (lane <= DD - 2) dgp = nd;
            } else if (p > 0) {
                // consumer: validate prefetched packets; fallback re-poll
                const unsigned expect = (unsigned)t;
                const u64* gslot = ginb + (size_t)((t - 1) & (RB - 1)) * (DD * 2);
                for (;;) {
                    int ok = 1;
                    if (lane < DD - 1)
                        ok = ((unsigned)(pfA >> 32) == expect) &
                             ((unsigned)(pfB >> 32) == expect);
                    if (lane == 0)
                        ok &= ((unsigned)(pfC0 >> 32) == expect) &
                              ((unsigned)(pfC1 >> 32) == expect);
                    if (__all(ok)) break;
                    if (lane < DD - 1) {
                        pfA = __hip_atomic_load((u64*)&gslot[(size_t)(lane + 1) * 2],
                                                __ATOMIC_RELAXED, __HIP_MEMORY_SCOPE_AGENT);
                        pfB = __hip_atomic_load((u64*)&gslot[(size_t)(lane + 1) * 2 + 1],
                                                __ATOMIC_RELAXED, __HIP_MEMORY_SCOPE_AGENT);
                    }
                    if (lane == 0) {
                        pfC0 = __hip_atomic_load((u64*)&gslot[0],
                                                 __ATOMIC_RELAXED, __HIP_MEMORY_SCOPE_AGENT);
                        pfC1 = __hip_atomic_load((u64*)&gslot[1],
                                                 __ATOMIC_RELAXED, __HIP_MEMORY_SCOPE_AGENT);
                    }
                }
                if (lane < DD - 1) { r1 = __uint_as_float((unsigned)pfA);
                                     r2 = __uint_as_float((unsigned)pfB); }
                float nd = dppshr(0.0f, r2);
                if (lane == 0) { bndUp = __uint_as_float((unsigned)pfC0);
                                 dgp   = __uint_as_float((unsigned)pfC1); }
                else if (lane <= DD - 2) dgp = nd;
                // ack value data-depends on loaded tag: cannot precede the loads
                if (lane == 0)
                    __hip_atomic_store(&acks[fin], (int)(pfC0 >> 32),
                                       __ATOMIC_RELAXED, __HIP_MEMORY_SCOPE_AGENT);
            } else {
                bndUp = BIGS;   // p==0, w==0: true boundary
            }
        }

        // ---- interval t compute ----
        const int kbase = t << 5;
        const int jj0 = kbase - imask;                  // j at d=0 (or very negative)

        // preload this interval's 32 consecutive weights into registers
        // (16x ds_read_b64; removes per-step LDS latency from the chain)
        const float* wp = &wlu[kbase + wq];
        float wreg[DD];
        #pragma unroll
        for (int h = 0; h < DD / 2; ++h) {
            float2 w2 = *reinterpret_cast<const float2*>(&wp[2 * h]);
            wreg[2 * h] = w2.x; wreg[2 * h + 1] = w2.y;
        }

        const float xf0 = xpreB;
        xv = xpreA;
        // issue next interval's x seeds now; full interval to complete
        { int cN  = min(max(kbase + DD - 1 - i, 0), NN - 1);
          int c0N = min(max(kbase + DD - i0, 0), NN - 1);
          xpreA = xs[cN]; xpreB = xs[c0N]; }

        if (i0 >= 0 && kbase >= i0 + 63) {
            // steady: every lane has j>=0 for all d; rows >1023 compute
            // garbage that is provably never consumed (dpp feeds upward only,
            // exch/cross-block publishes cover valid rows only)
            #pragma unroll
            for (int d = 0; d < DD; ++d) STEPBODY(d, 0);
        } else {
            #pragma unroll
            for (int d = 0; d < DD; ++d) STEPBODY(d, 1);
        }
        if (t == NT - 1) break;

        // intra-block publish: fresh lanes only (wave NW-1's slots are unread).
        // Quad-buffer overwrite gate: slot t&3 held interval t-4's finals,
        // consumed by wave w+1 at top of its interval t-3.
        if (w < NW - 1) {
            if (t >= EXB - 1) waitProg(&prog[w + 1], t - (EXB - 1));
            if (lane >= DD - 1)
                exch[t & (EXB - 1)][SW * w + lane] = make_float2(r1, r2);
        }
        // progress flag: release orders the exch data writes before it
        if (lane == 0)
            __hip_atomic_store(&prog[w], t, __ATOMIC_RELEASE,
                               __HIP_MEMORY_SCOPE_WORKGROUP);

        // consumer prefetch for next boundary (tag t+1, slot t&1): issued
        // early so fabric latency overlaps the next refresh/compute
        if (isCons) {
            const u64* gslot = ginb + (size_t)(t & (RB - 1)) * (DD * 2);
            if (lane < DD - 1) {
                pfA = __hip_atomic_load((u64*)&gslot[(size_t)(lane + 1) * 2],
                                        __ATOMIC_RELAXED, __HIP_MEMORY_SCOPE_AGENT);
                pfB = __hip_atomic_load((u64*)&gslot[(size_t)(lane + 1) * 2 + 1],
                                        __ATOMIC_RELAXED, __HIP_MEMORY_SCOPE_AGENT);
            }
            if (lane == 0) {
                pfC0 = __hip_atomic_load((u64*)&gslot[0],
                                         __ATOMIC_RELAXED, __HIP_MEMORY_SCOPE_AGENT);
                pfC1 = __hip_atomic_load((u64*)&gslot[1],
                                         __ATOMIC_RELAXED, __HIP_MEMORY_SCOPE_AGENT);
            }
        }
    }

    // after t=NT-1: r2 = R(i, 2046); cell (1023,1023) is at i=1023 (p=7,w=3,lane=62)
    if (i == NN - 1) partial[b] = r2 * INV_K2;
}

__global__ __launch_bounds__(64) void reduce_mean32(const float* __restrict__ partial,
                                                    float* __restrict__ out) {
    float v = (threadIdx.x < BATCH) ? partial[threadIdx.x] : 0.0f;
    #pragma unroll
    for (int off = 32; off > 0; off >>= 1) v += __shfl_down(v, off);
    if (threadIdx.x == 0) out[0] = v * (1.0f / (float)BATCH);
}

extern "C" void kernel_launch(void* const* d_in, const int* in_sizes, int n_in,
                              void* d_out, int out_size, void* d_ws, size_t ws_size,
                              hipStream_t stream) {
    const float* inp = (const float*)d_in[0];  // [B, N, 1]
    const float* tgt = (const float*)d_in[1];  // [B, N, 1]
    float* out = (float*)d_out;                // [1]

    float* partial = (float*)d_ws;                        // 32 floats
    int* acks  = (int*)((char*)d_ws + 128);               // 256 ints
    u64* gx    = (u64*)((char*)d_ws + 2048);              // 256*RB*DD*2 u64 = 256KB

    ws_init<<<129, 256, 0, stream>>>(acks, gx);
    sdtw_pipe8<<<BATCH * P, THREADS, 0, stream>>>(inp, tgt, partial, acks, gx);
    reduce_mean32<<<1, 64, 0, stream>>>(partial, out);
}

// Round 6
// 206.689 us; speedup vs baseline: 1.5704x; 1.0551x over previous
//
#include <hip/hip_runtime.h>
#include <math.h>

#define NN 1024
#define BATCH 32
#define P 8               // blocks per batch
#define NW 4              // waves per block
#define THREADS 256
#define DD 32             // diagonals per interval (needs SW >= DD-1, SW+DD <= 65)
#define SW 32             // row stride between waves
#define SPAN 160          // (NW-1)*SW + 64
#define NT 64             // ceil(2047/DD)
#define RB 4              // fabric ring slots per interface (power of 2); T >= RT/(RB-1)
#define EXB 4             // LDS exchange ring slots (power of 2)
#define WLN 2368          // per-block unified weight LUT length (covers m-range + guards)
#define GW 0.05f
#define K2 144.2695040888963f            // (1/gamma)*log2(e): scaled domain
#define INV_K2 0.0069314718055994531f    // gamma*ln2
#define BIGS 1.4426950408889634e11f      // 1e9 * K2

#define EXP2F(x) __builtin_amdgcn_exp2f(x)
#define LOG2F(x) __builtin_amdgcn_logf(x)   // v_log_f32 = log2

typedef unsigned long long u64;

// lanes 1..63 <- src[lane-1]; lane 0 <- oldv[0] (DPP wave_shr:1, bound_ctrl=false)
__device__ __forceinline__ float dppshr(float oldv, float src) {
    return __int_as_float(__builtin_amdgcn_update_dpp(
        __float_as_int(oldv), __float_as_int(src), 0x138, 0xF, 0xF, false));
}

// self-validating packet: {f32 value | u32 tag} in one atomic u64
__device__ __forceinline__ u64 pk(float v, unsigned tag) {
    return ((u64)tag << 32) | (u64)__float_as_uint(v);
}

// acquire-poll an LDS progress counter until >= want
__device__ __forceinline__ void waitProg(int* fp, int want) {
    while (__hip_atomic_load(fp, __ATOMIC_ACQUIRE, __HIP_MEMORY_SCOPE_WORKGROUP) < want)
        __builtin_amdgcn_s_sleep(1);
}

// zero acks[256] + all packet words (tags must not alias across runs)
// gx = 256 interfaces * RB * DD * 2 = 65536 u64 -> 256 blocks of 256
__global__ __launch_bounds__(256) void ws_init(int* __restrict__ acks,
                                               u64* __restrict__ gx) {
    if (blockIdx.x == 256) acks[threadIdx.x] = 0;
    else gx[(size_t)blockIdx.x * 256 + threadIdx.x] = 0;
}

// One DP step. DOMASK is compile-time 0/1; entry mask doubles as the i<0
// boundary (R(-1,j)=inf), so the wave containing rows i<0 keeps it forever.
#define STEPBODY(d, DOMASK) do {                                              \
        xv = dppshr(((d) == 0) ? xf0 : xv, xv);     /* x[k-i] flows diag */   \
        const float up = dppshr(((d) == 0) ? bndUp : r1, r1); /* R(i-1,k-1)*/ \
        const float dg = dgp;                                                 \
        const float left = r1;                                                \
        const float diff = ti - xv;                                           \
        const float dk = diff * diff * wreg[(d)];   /* K2-scaled cost */      \
        const float mn = fminf(fminf(dg, up), left);                          \
        const float md = __builtin_amdgcn_fmed3f(dg, up, left);               \
        const float mx = fmaxf(fmaxf(dg, up), left);                          \
        const float ss = 1.0f + EXP2F(mn - md) + EXP2F(mn - mx);              \
        float r = dk + mn - LOG2F(ss);                                        \
        if (DOMASK) r = (jj0 >= -(d)) ? r : BIGS;   /* entry-side mask */     \
        r2 = r1; r1 = r; dgp = up;                                            \
    } while (0)

// Overlapped-band wavefront soft-DTW, 8 CUs per batch.
// Round-10: ack-RT floor removal. R3/R4 calibration shows a 4,350cy/interval
// fixed cost invariant to sync style and waves/SIMD. Steady-state timing of
// the fabric ring gives period >= (ack round-trip)/(RB-1); RB=2 put the full
// device-scope atomic RT (~2-2.5k cy) on every interval. Now RB=4 (floor ->
// RT/3), plus: intra-block exchange pre-read at interval bottom (top refresh
// becomes register-only merge), and loop-carried wreg (next interval's weight
// ds_reads issue at current bottom) -- both strip LDS latency off the serial
// period. Free-run flag protocol (R5) retained so skew can equilibrate.
__global__ __launch_bounds__(THREADS) void sdtw_pipe8(
        const float* __restrict__ inp, const float* __restrict__ tgt,
        float* __restrict__ partial, int* __restrict__ acks,
        u64* __restrict__ gx)
{
    __shared__ __align__(16) float xs[NN];
    __shared__ __align__(16) float wlu[WLN];
    __shared__ float2 exch[EXB][SPAN];
    __shared__ int prog[NW];

    const int bid = blockIdx.x;
    const int b = bid & 31;          // same-batch stages share an XCD (bid%8 = b%8)
    const int p = bid >> 5;
    const int tid = threadIdx.x;
    const int w = tid >> 6;
    const int lane = tid & 63;

    // unified LUT: wlu[idx] = K2*sigma(G*(|m-1023|-512)), m = idx + mlo.
    // Per-block m range: m = k - 2i + 1023, k in [0,2047], i in [128p-31,128p+128]
    // -> [767-256p, 3132-256p]; out-of-range m only feeds masked/unread cells
    // (finite benign value K2). mlo odd + m0 odd -> idx even -> 8B aligned.
    const int mlo = 767 - 256 * p;
    for (int tdx = tid; tdx < NN; tdx += THREADS)
        xs[tdx] = inp[b * NN + tdx];
    for (int tdx = tid; tdx < WLN; tdx += THREADS) {
        int m = tdx + mlo;
        float val = K2;
        if ((unsigned)m <= 2046u)
            val = K2 / (1.0f + __expf(-GW * (fabsf((float)m - 1023.0f) - 512.0f)));
        wlu[tdx] = val;
    }
    if (tid < NW) prog[tid] = -1;

    const int i = 128 * p - (DD - 1) + SW * w + lane;   // owned row (may be OOB)
    const int i0 = i - lane;                            // wave's base row
    const bool rowValid = (unsigned)i < (unsigned)NN;
    int ic = min(max(i, 0), NN - 1);
    const float ti = tgt[b * NN + ic];
    const int imask = rowValid ? i : 0x3FFFFFFF;        // forces jj0 very negative
    // weight index at step d: (t<<5) + wq + d, wq = 256 + 256p - 2i (even, in [0,318])
    const int wq = 256 + 256 * p - 2 * i;

    float r1 = BIGS, r2 = BIGS;             // R(i,k-1), R(i,k-2), scaled by K2
    float dgp = (i == 0) ? 0.0f : BIGS;     // R(i-1,k-2) carry; R(-1,-1)=0
    float bndUp = BIGS;                     // lane-0 'up' feed at interval start
    float xv = 0.0f;                        // x[k - i] rotation register
    int ackC = 0;

    __syncthreads();                        // full sync once: LDS init done

    const int fin = b * P + p;              // inbound interface (p>0)
    const int fout = fin + 1;               // outbound interface (p<P-1)
    u64* gout = gx + (size_t)fout * (RB * DD * 2);
    u64* ginb = gx + (size_t)fin * (RB * DD * 2);

    const bool isProd = (w == NW - 1) && (p < P - 1);
    const bool isCons = (w == 0) && (p > 0);

    u64 pfA = 0, pfB = 0, pfC0 = 0, pfC1 = 0;   // consumer prefetch regs
    float nr1 = 0.0f, nr2 = 0.0f, nbx = 0.0f, nby = 0.0f;  // intra pre-read regs

    // ping-pong prefetch of the x rotation seeds for interval t=0
    int cP  = min(max(-1 - i, 0), NN - 1);
    int c0P = min(max(-i0, 0), NN - 1);
    float xpreA = xs[cP];       // -> xv init: x[kbase-1-i]
    float xpreB = xs[c0P];      // -> xf0:     x[kbase-i0]

    // loop-carried weight registers: preload interval t=0
    float wreg[DD];
    {
        const float* wp = &wlu[wq];
        #pragma unroll
        for (int h = 0; h < DD / 2; ++h) {
            float2 w2 = *reinterpret_cast<const float2*>(&wp[2 * h]);
            wreg[2 * h] = w2.x; wreg[2 * h + 1] = w2.y;
        }
    }

    for (int t = 0; t < NT; ++t) {
        if (t > 0) {
            // ---- deferred cross-block publish of interval t-1 (tag = t) ----
            // r1/r2 of lanes 31..62 still hold interval t-1 finals here
            // (register merge below only touches lanes 0..30).
            if (isProd) {
                if (t > RB) {                       // slot (t-1)&3 free? need ack >= t-RB
                    while (ackC < t - RB) {
                        __builtin_amdgcn_s_sleep(1);
                        ackC = __hip_atomic_load(&acks[fout], __ATOMIC_RELAXED,
                                                 __HIP_MEMORY_SCOPE_AGENT);
                    }
                }
                if (lane >= DD - 1 && lane < 63) {
                    u64* gq = gout + (size_t)((t - 1) & (RB - 1)) * (DD * 2)
                                   + (size_t)(lane - (DD - 1)) * 2;
                    __hip_atomic_store(&gq[0], pk(r1, (unsigned)t),
                                       __ATOMIC_RELAXED, __HIP_MEMORY_SCOPE_AGENT);
                    __hip_atomic_store(&gq[1], pk(r2, (unsigned)t),
                                       __ATOMIC_RELAXED, __HIP_MEMORY_SCOPE_AGENT);
                }
                // ack prefetch for next gate; latency hides under inner loop
                ackC = __hip_atomic_load(&acks[fout], __ATOMIC_RELAXED,
                                         __HIP_MEMORY_SCOPE_AGENT);
            }
            // ---- refresh stale lanes (0..30) + boundary feed ----
            if (w > 0) {
                // register-only merge (data pre-read at bottom of t-1)
                if (lane < DD - 1) { r1 = nr1; r2 = nr2; }
                float nd = dppshr(0.0f, r2);
                if (lane == 0)           { bndUp = nbx; dgp = nby; }
                else if (lane <= DD - 2) dgp = nd;
            } else if (p > 0) {
                // consumer: validate prefetched packets; fallback re-poll
                const unsigned expect = (unsigned)t;
                const u64* gslot = ginb + (size_t)((t - 1) & (RB - 1)) * (DD * 2);
                for (;;) {
                    int ok = 1;
                    if (lane < DD - 1)
                        ok = ((unsigned)(pfA >> 32) == expect) &
                             ((unsigned)(pfB >> 32) == expect);
                    if (lane == 0)
                        ok &= ((unsigned)(pfC0 >> 32) == expect) &
                              ((unsigned)(pfC1 >> 32) == expect);
                    if (__all(ok)) break;
                    if (lane < DD - 1) {
                        pfA = __hip_atomic_load((u64*)&gslot[(size_t)(lane + 1) * 2],
                                                __ATOMIC_RELAXED, __HIP_MEMORY_SCOPE_AGENT);
                        pfB = __hip_atomic_load((u64*)&gslot[(size_t)(lane + 1) * 2 + 1],
                                                __ATOMIC_RELAXED, __HIP_MEMORY_SCOPE_AGENT);
                    }
                    if (lane == 0) {
                        pfC0 = __hip_atomic_load((u64*)&gslot[0],
                                                 __ATOMIC_RELAXED, __HIP_MEMORY_SCOPE_AGENT);
                        pfC1 = __hip_atomic_load((u64*)&gslot[1],
                                                 __ATOMIC_RELAXED, __HIP_MEMORY_SCOPE_AGENT);
                    }
                }
                if (lane < DD - 1) { r1 = __uint_as_float((unsigned)pfA);
                                     r2 = __uint_as_float((unsigned)pfB); }
                float nd = dppshr(0.0f, r2);
                if (lane == 0) { bndUp = __uint_as_float((unsigned)pfC0);
                                 dgp   = __uint_as_float((unsigned)pfC1); }
                else if (lane <= DD - 2) dgp = nd;
                // ack value data-depends on loaded tag: cannot precede the loads
                if (lane == 0)
                    __hip_atomic_store(&acks[fin], (int)(pfC0 >> 32),
                                       __ATOMIC_RELAXED, __HIP_MEMORY_SCOPE_AGENT);
            } else {
                bndUp = BIGS;   // p==0, w==0: true boundary
            }
        }

        // ---- interval t compute ----
        const int kbase = t << 5;
        const int jj0 = kbase - imask;                  // j at d=0 (or very negative)

        const float xf0 = xpreB;
        xv = xpreA;
        // issue next interval's x seeds now; full interval to complete
        { int cN  = min(max(kbase + DD - 1 - i, 0), NN - 1);
          int c0N = min(max(kbase + DD - i0, 0), NN - 1);
          xpreA = xs[cN]; xpreB = xs[c0N]; }

        if (i0 >= 0 && kbase >= i0 + 63) {
            // steady: every lane has j>=0 for all d; rows >1023 compute
            // garbage that is provably never consumed (dpp feeds upward only,
            // exch/cross-block publishes cover valid rows only)
            #pragma unroll
            for (int d = 0; d < DD; ++d) STEPBODY(d, 0);
        } else {
            #pragma unroll
            for (int d = 0; d < DD; ++d) STEPBODY(d, 1);
        }
        if (t == NT - 1) break;

        // ---- interval bottom: publish, pre-read, prefetch ----
        // intra-block publish: fresh lanes only (wave NW-1's slots are unread).
        // Ring overwrite gate: slot t&3 held t-4's finals; reader w+1 pre-read
        // them at its bottom-of-(t-4), strictly before it set prog[w+1]=t-3.
        if (w < NW - 1) {
            if (t >= EXB - 1) waitProg(&prog[w + 1], t - (EXB - 1));
            if (lane >= DD - 1)
                exch[t & (EXB - 1)][SW * w + lane] = make_float2(r1, r2);
        }
        // progress flag: release orders the exch writes (and prior reads)
        if (lane == 0)
            __hip_atomic_store(&prog[w], t, __ATOMIC_RELEASE,
                               __HIP_MEMORY_SCOPE_WORKGROUP);

        // preload next interval's weights (completes under the boundary glue)
        {
            const float* wp = &wlu[((t + 1) << 5) + wq];
            #pragma unroll
            for (int h = 0; h < DD / 2; ++h) {
                float2 w2 = *reinterpret_cast<const float2*>(&wp[2 * h]);
                wreg[2 * h] = w2.x; wreg[2 * h + 1] = w2.y;
            }
        }

        // intra-block pre-read of neighbor's interval-t finals (register merge
        // at top of t+1): wait for neighbor, then read its slot t&3.
        if (w > 0) {
            waitProg(&prog[w - 1], t);
            const int buf = t & (EXB - 1);
            if (lane < DD - 1) { float2 vv = exch[buf][SW * w + lane]; nr1 = vv.x; nr2 = vv.y; }
            float2 bv = exch[buf][SW * w - 1];
            nbx = bv.x; nby = bv.y;
        }

        // consumer prefetch for next boundary (tag t+1, slot t&3): issued
        // early so fabric latency overlaps the loop-back + next validate
        if (isCons) {
            const u64* gslot = ginb + (size_t)(t & (RB - 1)) * (DD * 2);
            if (lane < DD - 1) {
                pfA = __hip_atomic_load((u64*)&gslot[(size_t)(lane + 1) * 2],
                                        __ATOMIC_RELAXED, __HIP_MEMORY_SCOPE_AGENT);
                pfB = __hip_atomic_load((u64*)&gslot[(size_t)(lane + 1) * 2 + 1],
                                        __ATOMIC_RELAXED, __HIP_MEMORY_SCOPE_AGENT);
            }
            if (lane == 0) {
                pfC0 = __hip_atomic_load((u64*)&gslot[0],
                                         __ATOMIC_RELAXED, __HIP_MEMORY_SCOPE_AGENT);
                pfC1 = __hip_atomic_load((u64*)&gslot[1],
                                         __ATOMIC_RELAXED, __HIP_MEMORY_SCOPE_AGENT);
            }
        }
    }

    // after t=NT-1: r2 = R(i, 2046); cell (1023,1023) is at i=1023 (p=7,w=3,lane=62)
    if (i == NN - 1) partial[b] = r2 * INV_K2;
}

__global__ __launch_bounds__(64) void reduce_mean32(const float* __restrict__ partial,
                                                    float* __restrict__ out) {
    float v = (threadIdx.x < BATCH) ? partial[threadIdx.x] : 0.0f;
    #pragma unroll
    for (int off = 32; off > 0; off >>= 1) v += __shfl_down(v, off);
    if (threadIdx.x == 0) out[0] = v * (1.0f / (float)BATCH);
}

extern "C" void kernel_launch(void* const* d_in, const int* in_sizes, int n_in,
                              void* d_out, int out_size, void* d_ws, size_t ws_size,
                              hipStream_t stream) {
    const float* inp = (const float*)d_in[0];  // [B, N, 1]
    const float* tgt = (const float*)d_in[1];  // [B, N, 1]
    float* out = (float*)d_out;                // [1]

    float* partial = (float*)d_ws;                        // 32 floats
    int* acks  = (int*)((char*)d_ws + 128);               // 256 ints
    u64* gx    = (u64*)((char*)d_ws + 2048);              // 256*RB*DD*2 u64 = 512KB

    ws_init<<<257, 256, 0, stream>>>(acks, gx);
    sdtw_pipe8<<<BATCH * P, THREADS, 0, stream>>>(inp, tgt, partial, acks, gx);
    reduce_mean32<<<1, 64, 0, stream>>>(partial, out);
}